// Round 1
// 69.166 us; speedup vs baseline: 1.0072x; 1.0072x over previous
//
#include <hip/hip_runtime.h>

#define BB 4
#define NN 4096
#define TPB 1024             // 16 waves
#define IBL 32               // i's per block = 8 lane-slots x IPT=4
#define IPT 4                // i's per thread
#define STREAMS 128          // 16 waves x 8 octet-streams
#define JPT (NN / STREAMS)   // 32 j's per stream, interleaved stride 128
#define GRP 2                // LDS prefetch depth (keeps VGPR < 64)
#define RSTRIDE 100          // reduction row stride in dwords (100%32=4 -> <=2-way banks)

#if __has_builtin(__builtin_amdgcn_sqrtf)
  #define FAST_SQRT __builtin_amdgcn_sqrtf
#else
  #define FAST_SQRT sqrtf
#endif

__device__ __forceinline__ float clip1(float x) {
    return fminf(fmaxf(x, -1.0f), 1.0f);   // -> v_med3_f32
}

// ONE dispatch, no workspace. Same skeleton as R-prev (512 blocks = 2/CU via
// 80 KiB LDS, 32 waves/CU), but the main loop is restructured against the
// LDS-read-pipe bottleneck:
//  * IPT 2 -> 4: one ds_read_b128 now feeds 64 lanes x 4 i = 256 pairs
//    (halves LDS instructions per pair). Per-i regs cut to 8 by deriving
//    xi = -0.5*m2x and n2 = (1+ri)^2 - thr on the (16.5%-taken) hit path.
//  * Interleaved j-streams: stream s = w*8+o handles j = s + k*128. Read
//    addr = s*16B + k*2048B -> bank quad 4*o, so a wave's 8 octets hit 8
//    DISTINCT bank quads (old layout: jbase delta 1024B -> same quad ->
//    4-way conflict). k*2048 folds into ds immediate offsets.
//  * rad[j] hit-path read: bank = s mod 32 -> 8 distinct banks per wave.
// Early-out bound kept: target = max(1,ri+rj) <= 1+ri (radii in [0,1)), so
// skip when sd >= thr = (1+ri)^2 - n2i. Diagonal: ex = 0.5*m2x + xi = 0
// exactly -> clip(0) = 0, matches reference.
__global__ __launch_bounds__(TPB, 8) void ncp_one(
    const float* __restrict__ coords,   // [BB,NN,3]
    const float* __restrict__ radii,    // [BB,NN]
    float* __restrict__ out)
{
    __shared__ __align__(16) char smem[81920];   // 64 KB pts4 + 16 KB rad
    float4* pts = (float4*)smem;            // [NN] (x,y,z,||p||^2)
    float*  rad = (float*)(smem + 65536);   // [NN]
    float*  red = (float*)smem;             // phase 2: [STREAMS][RSTRIDE] (50 KB)

    const int b = blockIdx.z;
    const int ibase = blockIdx.x * IBL;

    for (int p = threadIdx.x; p < NN; p += TPB) {
        const int g = b * NN + p;
        const float x = coords[3 * g + 0];
        const float y = coords[3 * g + 1];
        const float z = coords[3 * g + 2];
        pts[p] = make_float4(x, y, z, fmaf(z, z, fmaf(y, y, x * x)));
        rad[p] = radii[g];
    }
    __syncthreads();

    const int l  = threadIdx.x & 63;
    const int li = l & 7;               // i lane-slot 0..7
    const int o  = l >> 3;              // octet 0..7
    const int w  = threadIdx.x >> 6;    // wave 0..15
    const int s  = w * 8 + o;           // stream 0..127: j = s + k*128

    float m2x[IPT], m2y[IPT], m2z[IPT], thr[IPT], ri[IPT];
    float ax[IPT], ay[IPT], az[IPT];
    #pragma unroll
    for (int t = 0; t < IPT; ++t) {
        const float4 me = pts[ibase + li + 8 * t];
        const float  r  = rad[ibase + li + 8 * t];
        m2x[t] = -2.0f * me.x;
        m2y[t] = -2.0f * me.y;
        m2z[t] = -2.0f * me.z;
        ri[t]  = r;
        thr[t] = (1.0f + r) * (1.0f + r) - me.w;   // tight skip bound
        ax[t] = 0.0f; ay[t] = 0.0f; az[t] = 0.0f;
    }

    const float4* __restrict__ pj = pts + s;   // stride-128 j walk
    const float*  __restrict__ rj = rad + s;

    for (int k0 = 0; k0 < JPT; k0 += GRP) {
        float4 c[GRP];
        #pragma unroll
        for (int g = 0; g < GRP; ++g)
            c[g] = pj[(k0 + g) * STREAMS];      // conflict-free 8-way broadcast
        #pragma unroll
        for (int g = 0; g < GRP; ++g) {
            #pragma unroll
            for (int t = 0; t < IPT; ++t) {
                // c.w == nj precomputed: miss path = 3 fma + 1 cmp per pair
                const float sd = fmaf(m2z[t], c[g].z,
                                 fmaf(m2y[t], c[g].y,
                                 fmaf(m2x[t], c[g].x, c[g].w)));
                if (__any(sd < thr[t])) {
                    const float rjv  = rj[(k0 + g) * STREAMS]; // taken only
                    const float sp1  = 1.0f + ri[t];
                    const float n2   = fmaf(sp1, sp1, -thr[t]);  // = ||pi||^2
                    const float dist = FAST_SQRT(fmaxf(sd + n2, 0.0f));
                    const float tgt  = fmaxf(1.0f, ri[t] + rjv);
                    const float p    = fmaxf(tgt - dist, 0.0f);
                    const float ex   = fmaf(0.5f, m2x[t], c[g].x); // = -dx
                    const float ey   = fmaf(0.5f, m2y[t], c[g].y);
                    const float ez   = fmaf(0.5f, m2z[t], c[g].z);
                    ax[t] = fmaf(p, -clip1(ex), ax[t]);  // neg folds to modifier
                    ay[t] = fmaf(p, -clip1(ey), ay[t]);
                    az[t] = fmaf(p, -clip1(ez), az[t]);
                }
            }
        }
    }

    __syncthreads();                    // all pts/rad reads done before reuse
    #pragma unroll
    for (int t = 0; t < IPT; ++t) {
        const int r0 = s * RSTRIDE + (li + 8 * t) * 3;
        red[r0 + 0] = ax[t];
        red[r0 + 1] = ay[t];
        red[r0 + 2] = az[t];
    }
    __syncthreads();

    if (threadIdx.x < IBL * 3) {        // 96 outputs per block
        float acc = 0.0f;
        #pragma unroll 8
        for (int ss = 0; ss < STREAMS; ++ss)
            acc += red[ss * RSTRIDE + threadIdx.x];
        const int oidx = (b * NN + ibase) * 3 + threadIdx.x;
        out[oidx] = fmaf(0.1f / (float)NN, acc, coords[oidx]);
    }
}

extern "C" void kernel_launch(void* const* d_in, const int* in_sizes, int n_in,
                              void* d_out, int out_size, void* d_ws, size_t ws_size,
                              hipStream_t stream) {
    const float* coords = (const float*)d_in[0];
    const float* radii  = (const float*)d_in[1];
    float* out = (float*)d_out;
    (void)d_ws; (void)ws_size;

    ncp_one<<<dim3(NN / IBL, 1, BB), TPB, 0, stream>>>(coords, radii, out);
}

// Round 2
// 68.594 us; speedup vs baseline: 1.0156x; 1.0083x over previous
//
#include <hip/hip_runtime.h>

#define BB 4
#define NN 4096
#define TPB 1024             // 16 waves
#define IBL 32               // i's per block = 8 lane-slots x IPT=4
#define IPT 4                // i's per thread
#define STREAMS 128          // 16 waves x 8 octet-streams
#define JPT (NN / STREAMS)   // 32 j's per stream, interleaved stride 128
#define GRP 2                // LDS prefetch depth (keeps VGPR < 64)
#define RSTRIDE 100          // reduction row stride in dwords (100%32=4 -> <=2-way banks)

#if __has_builtin(__builtin_amdgcn_sqrtf)
  #define FAST_SQRT __builtin_amdgcn_sqrtf
#else
  #define FAST_SQRT sqrtf
#endif

__device__ __forceinline__ float clip1(float x) {
    return fminf(fmaxf(x, -1.0f), 1.0f);   // -> v_med3_f32
}

// R2 = R1 skeleton (512 blocks = 2/CU, 32 waves/CU, interleaved conflict-free
// j-streams, IPT=4) + last measurable kernel-side shavings. This round doubles
// as the harness-floor probe: R0->R1 restructured the whole main loop for
// -0.5us, and ncp_one never shows in top-5 (so kernel < 39us while dur=69us
// includes a 40us 256MiB ws re-poison fill already at 84% HBM peak).
//  * staging: 16 scalar global loads/thread -> 4x dwordx4 (3 coord float4 +
//    1 radii float4), cuts the pre-barrier ramp.
//  * epilogue: serial 96-thread x 128-stream reduce -> 384x32 + 96x4 tree
//    (partials in the rad area, which is dead by then).
//  * main loop unchanged: miss path = 3 fma + cmp, conflict-free 8-way
//    broadcast ds_read_b128, tight early-out thr = (1+ri)^2 - n2i.
// If dur_us stays ~69, remaining time is harness floor -> ROOFLINE.
__global__ __launch_bounds__(TPB, 8) void ncp_one(
    const float* __restrict__ coords,   // [BB,NN,3]
    const float* __restrict__ radii,    // [BB,NN]
    float* __restrict__ out)
{
    __shared__ __align__(16) char smem[81920];   // 64 KB pts4 + 16 KB rad
    float4* pts = (float4*)smem;            // [NN] (x,y,z,||p||^2)
    float*  rad = (float*)(smem + 65536);   // [NN]
    float*  red = (float*)smem;             // phase 2: [STREAMS][RSTRIDE] (50 KB)
    float*  red2 = (float*)(smem + 65536);  // phase 2b: [4][96] partials

    const int b = blockIdx.z;
    const int ibase = blockIdx.x * IBL;
    const int t = threadIdx.x;

    {   // vectorized staging: 4 consecutive points per thread, 48 B coords
        const float4* cb = (const float4*)(coords + (size_t)b * NN * 3);
        const float4  f0 = cb[3 * t + 0];
        const float4  f1 = cb[3 * t + 1];
        const float4  f2 = cb[3 * t + 2];
        const float4  r4 = ((const float4*)(radii + (size_t)b * NN))[t];
        const int p0 = 4 * t;
        pts[p0 + 0] = make_float4(f0.x, f0.y, f0.z,
                                  fmaf(f0.z, f0.z, fmaf(f0.y, f0.y, f0.x * f0.x)));
        pts[p0 + 1] = make_float4(f0.w, f1.x, f1.y,
                                  fmaf(f1.y, f1.y, fmaf(f1.x, f1.x, f0.w * f0.w)));
        pts[p0 + 2] = make_float4(f1.z, f1.w, f2.x,
                                  fmaf(f2.x, f2.x, fmaf(f1.w, f1.w, f1.z * f1.z)));
        pts[p0 + 3] = make_float4(f2.y, f2.z, f2.w,
                                  fmaf(f2.w, f2.w, fmaf(f2.z, f2.z, f2.y * f2.y)));
        *(float4*)&rad[p0] = r4;
    }
    __syncthreads();

    const int l  = t & 63;
    const int li = l & 7;               // i lane-slot 0..7
    const int o  = l >> 3;              // octet 0..7
    const int w  = t >> 6;              // wave 0..15
    const int s  = w * 8 + o;           // stream 0..127: j = s + k*128

    float m2x[IPT], m2y[IPT], m2z[IPT], thr[IPT], ri[IPT];
    float ax[IPT], ay[IPT], az[IPT];
    #pragma unroll
    for (int u = 0; u < IPT; ++u) {
        const float4 me = pts[ibase + li + 8 * u];
        const float  r  = rad[ibase + li + 8 * u];
        m2x[u] = -2.0f * me.x;
        m2y[u] = -2.0f * me.y;
        m2z[u] = -2.0f * me.z;
        ri[u]  = r;
        thr[u] = (1.0f + r) * (1.0f + r) - me.w;   // tight skip bound
        ax[u] = 0.0f; ay[u] = 0.0f; az[u] = 0.0f;
    }

    const float4* __restrict__ pj = pts + s;   // stride-128 j walk
    const float*  __restrict__ rj = rad + s;

    for (int k0 = 0; k0 < JPT; k0 += GRP) {
        float4 c[GRP];
        #pragma unroll
        for (int g = 0; g < GRP; ++g)
            c[g] = pj[(k0 + g) * STREAMS];      // conflict-free 8-way broadcast
        #pragma unroll
        for (int g = 0; g < GRP; ++g) {
            #pragma unroll
            for (int u = 0; u < IPT; ++u) {
                // c.w == nj precomputed: miss path = 3 fma + 1 cmp per pair
                const float sd = fmaf(m2z[u], c[g].z,
                                 fmaf(m2y[u], c[g].y,
                                 fmaf(m2x[u], c[g].x, c[g].w)));
                if (__any(sd < thr[u])) {
                    const float rjv  = rj[(k0 + g) * STREAMS]; // taken only
                    const float sp1  = 1.0f + ri[u];
                    const float n2   = fmaf(sp1, sp1, -thr[u]);  // = ||pi||^2
                    const float dist = FAST_SQRT(fmaxf(sd + n2, 0.0f));
                    const float tgt  = fmaxf(1.0f, ri[u] + rjv);
                    const float p    = fmaxf(tgt - dist, 0.0f);
                    const float ex   = fmaf(0.5f, m2x[u], c[g].x); // = -dx
                    const float ey   = fmaf(0.5f, m2y[u], c[g].y);
                    const float ez   = fmaf(0.5f, m2z[u], c[g].z);
                    ax[u] = fmaf(p, -clip1(ex), ax[u]);  // neg folds to modifier
                    ay[u] = fmaf(p, -clip1(ey), ay[u]);
                    az[u] = fmaf(p, -clip1(ez), az[u]);
                }
            }
        }
    }

    __syncthreads();                    // all pts/rad reads done before reuse
    #pragma unroll
    for (int u = 0; u < IPT; ++u) {
        const int r0 = s * RSTRIDE + (li + 8 * u) * 3;
        red[r0 + 0] = ax[u];
        red[r0 + 1] = ay[u];
        red[r0 + 2] = az[u];
    }
    __syncthreads();

    if (t < 384) {                      // level 1: 4 chunks x 32 streams
        const int oc    = t % 96;       // output component 0..95
        const int chunk = t / 96;       // 0..3
        float acc = 0.0f;
        const int sbase = chunk * 32;
        #pragma unroll 8
        for (int ss = 0; ss < 32; ++ss)     // ascending ss == ascending j
            acc += red[(sbase + ss) * RSTRIDE + oc];
        red2[chunk * 96 + oc] = acc;
    }
    __syncthreads();

    if (t < 96) {                       // level 2: 4 partials + writeout
        const float acc = ((red2[t] + red2[96 + t]) + red2[192 + t]) + red2[288 + t];
        const int oidx = (b * NN + ibase) * 3 + t;
        out[oidx] = fmaf(0.1f / (float)NN, acc, coords[oidx]);
    }
}

extern "C" void kernel_launch(void* const* d_in, const int* in_sizes, int n_in,
                              void* d_out, int out_size, void* d_ws, size_t ws_size,
                              hipStream_t stream) {
    const float* coords = (const float*)d_in[0];
    const float* radii  = (const float*)d_in[1];
    float* out = (float*)d_out;
    (void)d_ws; (void)ws_size;

    ncp_one<<<dim3(NN / IBL, 1, BB), TPB, 0, stream>>>(coords, radii, out);
}